// Round 6
// baseline (717.740 us; speedup 1.0000x reference)
//
#include <hip/hip_runtime.h>

// GCN 2-layer forward. CSR-gather, bf16 payloads (stride-64, 128 B rows).
// Pipeline (4 dispatches):
//   partmm1 (edge partition + hs1 = bf16(x@W1))
//   build   (1024-thr wave-parallel CSR build + hs1 *= dinv)
//   agg1mm2 (64-node blocks: gather h1 -> f32 LDS, then TILED h1@W2 -> hs2)
//   agg2    (out = dinv*gather + b2)
//
// R6 = R5 bugfix. R5 crashed: deep-unrolled gather dereferenced myoff from
// lanes beyond the node's row (uninitialized adj slots -> garbage offsets ->
// OOB). Fix: per-lane VALUE sanitize — myoff = (lane < m) ? adj[idx]<<6 : 0.
// R5 structure kept: 16 row-loads in flight per 64-edge block (deep MLP);
// Htm[m][F1+4] transposed (h1 store = 1 float4/lane conflict-free; mm2 reads
// strided-m, 2-way).

#define FIN 128
#define F1  64
#define F2  41
#define FP  64     // payload row stride (bf16 elems): 128 B, 2 lines, aligned

#define BSH    8                 // bucket = dst >> 8 (256 nodes/bucket)
#define BCAP   6144              // per-bucket adj window (mean 4096, >30 sigma)
#define CHUNK_P 4096             // edges per part block (16/thread)

#define MT 128                   // mm1 GEMM M-tile
#define KC 16                    // mm1 GEMM K-chunk
#define AMT 64                   // agg1mm2 nodes per block

#define SMEM_BYTES 24576         // union: part 19.5 KB / mm1 24.6 KB -> 6 blk/CU

__device__ __forceinline__ unsigned short f2bf(float f) {
    unsigned u = __builtin_bit_cast(unsigned, f);
    u += 0x7FFFu + ((u >> 16) & 1u);           // RNE
    return (unsigned short)(u >> 16);
}
__device__ __forceinline__ float bf2f(unsigned short h) {
    unsigned u = ((unsigned)h) << 16;
    return __builtin_bit_cast(float, u);
}

// ---- fused: blocks [0,nchunks) = edge partition; rest = layer-1 GEMM -------
__global__ __launch_bounds__(256) void k_partmm1(
    const int* __restrict__ src, const int* __restrict__ dst,
    unsigned short* __restrict__ offs, int* __restrict__ pairs,
    int E, int nchunks, int NB,
    const float* __restrict__ x, const float* __restrict__ W1,
    unsigned short* __restrict__ hs, int n) {
    __shared__ alignas(16) char smem[SMEM_BYTES];
    int tid = threadIdx.x;
    if ((int)blockIdx.x < nchunks) {
        // ---------------- PART (19.5 KB): LDS bucket-sort, coalesced out ----
        int* hist = (int*)smem;            // 512 ints (2 KB)
        int* lex  = hist + 512;            // 256 (1 KB)
        int* limg = lex + 256;             // CHUNK_P ints (16 KB)
        int e0  = blockIdx.x * CHUNK_P;
        int ds[CHUNK_P / 256], ss[CHUNK_P / 256];
#pragma unroll
        for (int j = 0; j < CHUNK_P / 256; j++) {
            int e = e0 + j * 256 + tid;
            if (e < E) { ds[j] = dst[e]; ss[j] = src[e]; } else ds[j] = -1;
        }
        hist[tid] = 0; hist[tid + 256] = 0;
        __syncthreads();
#pragma unroll
        for (int j = 0; j < CHUNK_P / 256; j++)
            if (ds[j] >= 0) atomicAdd(&hist[ds[j] >> BSH], 1);
        __syncthreads();
        int b0 = 2 * tid, b1 = 2 * tid + 1;
        int c0 = hist[b0], c1 = hist[b1];
        int s  = c0 + c1;
        lex[tid] = s;
        __syncthreads();
        for (int off = 1; off < 256; off <<= 1) {
            int v = lex[tid];
            int a = (tid >= off) ? lex[tid - off] : 0;
            __syncthreads();
            lex[tid] = v + a;
            __syncthreads();
        }
        int incl = lex[tid];
        int ex0 = incl - s;
        int ex1 = ex0 + c0;
        // per-chunk bucket offset row (u16): starts[b], plus total at [NB]
        unsigned short* orow = offs + (size_t)blockIdx.x * (NB + 1);
        if (b0 < NB) orow[b0] = (unsigned short)ex0;
        if (b1 < NB) orow[b1] = (unsigned short)ex1;
        if (tid == 255) orow[NB] = (unsigned short)incl;
        hist[b0] = ex0; hist[b1] = ex1;
        __syncthreads();
#pragma unroll
        for (int j = 0; j < CHUNK_P / 256; j++) {
            if (ds[j] >= 0) {
                int b = ds[j] >> BSH;
                int p = atomicAdd(&hist[b], 1);
                limg[p] = (ss[j] << BSH) | (ds[j] & 255);
            }
        }
        __syncthreads();
        int tot = lex[255];
        int* pout = pairs + (size_t)blockIdx.x * CHUNK_P;
        for (int k = tid; k < tot; k += 256)   // fully coalesced
            pout[k] = limg[k];
    } else {
        // ---------------- MM1: hs1 = bf16(x @ W1), UNSCALED (24.6 KB) -------
        unsigned short* Ws = (unsigned short*)smem;      // 16 KB, W1 as bf16
        float (*As)[MT] = (float(*)[MT])(smem + FIN * F1 * 2);  // 8 KB
        int n0 = ((int)blockIdx.x - nchunks) * MT;
#pragma unroll
        for (int j = 0; j < 8; j++) {
            int f = j * 256 + tid;                       // float4 index (2048)
            float4 w4 = ((const float4*)W1)[f];
            ushort4 o = { f2bf(w4.x), f2bf(w4.y), f2bf(w4.z), f2bf(w4.w) };
            ((ushort4*)Ws)[f] = o;
        }
        int m0 = (tid & 15) * 8;
        int c0 = (tid >> 4) * 4;
        int m_l = tid & 127;
        int kh  = (tid >> 7) * 8;
        bool mvalid = (n0 + m_l) < n;
        const float* xrow = x + (size_t)(n0 + m_l) * FIN + kh;
        float acc[8][4] = {};
        for (int kc = 0; kc < FIN; kc += KC) {
            __syncthreads();
            float4 v0 = mvalid ? *(const float4*)(xrow + kc)     : float4{0.f,0.f,0.f,0.f};
            float4 v1 = mvalid ? *(const float4*)(xrow + kc + 4) : float4{0.f,0.f,0.f,0.f};
            As[kh + 0][m_l] = v0.x; As[kh + 1][m_l] = v0.y;
            As[kh + 2][m_l] = v0.z; As[kh + 3][m_l] = v0.w;
            As[kh + 4][m_l] = v1.x; As[kh + 5][m_l] = v1.y;
            As[kh + 6][m_l] = v1.z; As[kh + 7][m_l] = v1.w;
            __syncthreads();
#pragma unroll
            for (int k = 0; k < KC; k++) {
                float4 a0 = *(const float4*)&As[k][m0];
                float4 a1 = *(const float4*)&As[k][m0 + 4];
                ushort4 wq = *(const ushort4*)&Ws[(kc + k) * F1 + c0];
                float wx = bf2f(wq.x), wy = bf2f(wq.y);
                float wz = bf2f(wq.z), ww = bf2f(wq.w);
                float a[8] = {a0.x, a0.y, a0.z, a0.w, a1.x, a1.y, a1.z, a1.w};
#pragma unroll
                for (int i = 0; i < 8; i++) {
                    acc[i][0] += a[i] * wx;
                    acc[i][1] += a[i] * wy;
                    acc[i][2] += a[i] * wz;
                    acc[i][3] += a[i] * ww;
                }
            }
        }
#pragma unroll
        for (int i = 0; i < 8; i++) {
            int node = n0 + m0 + i;
            if (node < n) {
                ushort4 o = { f2bf(acc[i][0]), f2bf(acc[i][1]),
                              f2bf(acc[i][2]), f2bf(acc[i][3]) };
                *(ushort4*)&hs[((size_t)node << 6) + c0] = o;
            }
        }
    }
}

// ---- pass 2: wave-parallel per-bucket CSR build + tail-scale hs1 -----------
__global__ __launch_bounds__(1024) void k_build(
    const unsigned short* __restrict__ offs, const int* __restrict__ pairs,
    int nchunks, int NB, int* __restrict__ adj,
    int2* __restrict__ rowinfo, float* __restrict__ dinv,
    unsigned short* __restrict__ hs1, int n) {
    __shared__ int lcnt[256];
    __shared__ int lex[256];
    __shared__ int lcur[256];
    __shared__ float ldv[256];
    int tid  = threadIdx.x;
    int wave = tid >> 6;               // 16 waves
    int lane = tid & 63;
    int b    = blockIdx.x;
    int NB1  = NB + 1;
    int node0 = b << BSH;
    int base  = b * BCAP;              // static adj window

    if (tid < 256) lcnt[tid] = 0;
    __syncthreads();
    // pass 1: per-node histogram; each wave sweeps whole segments
    for (int c = wave; c < nchunks; c += 16) {
        int s0 = offs[(size_t)c * NB1 + b];
        int s1 = offs[(size_t)c * NB1 + b + 1];
        const int* pc = pairs + (size_t)c * CHUNK_P;
        for (int i = s0 + lane; i < s1; i += 64)
            atomicAdd(&lcnt[pc[i] & 255], 1);
    }
    __syncthreads();
    int own = (tid < 256) ? lcnt[tid] : 0;
    if (tid < 256) lex[tid] = own;
    __syncthreads();
    for (int off = 1; off < 256; off <<= 1) {
        int val = 0, add = 0;
        if (tid < 256) {
            val = lex[tid];
            add = (tid >= off) ? lex[tid - off] : 0;
        }
        __syncthreads();
        if (tid < 256) lex[tid] = val + add;
        __syncthreads();
    }
    int excl = (tid < 256) ? (lex[tid] - own) : 0;
    float dvn = rsqrtf((float)own + 1.0f);
    if (tid < 256) { lcur[tid] = excl; ldv[tid] = dvn; }
    __syncthreads();
    // pass 2: place src ids into the adj window, wave-parallel
    for (int c = wave; c < nchunks; c += 16) {
        int s0 = offs[(size_t)c * NB1 + b];
        int s1 = offs[(size_t)c * NB1 + b + 1];
        const int* pc = pairs + (size_t)c * CHUNK_P;
        for (int i = s0 + lane; i < s1; i += 64) {
            int pk  = pc[i];
            int pos = atomicAdd(&lcur[pk & 255], 1);
            adj[base + pos] = pk >> BSH;
        }
    }
    int node = node0 + tid;
    if (tid < 256 && node < n) {
        rowinfo[node] = make_int2(base + excl, own);
        dinv[node]    = dvn;
    }
    // ---- tail: hs1[node] *= dinv[node] for this bucket's 256 nodes --------
    for (int u = tid; u < 2048; u += 1024) {
        int nd = node0 + (u >> 3);
        if (nd >= n) break;
        float dv = ldv[u >> 3];
        ushort4* p = (ushort4*)&hs1[((size_t)nd << 6) + (u & 7) * 8];
        ushort4 a = p[0], c = p[1];
        a.x = f2bf(bf2f(a.x) * dv); a.y = f2bf(bf2f(a.y) * dv);
        a.z = f2bf(bf2f(a.z) * dv); a.w = f2bf(bf2f(a.w) * dv);
        c.x = f2bf(bf2f(c.x) * dv); c.y = f2bf(bf2f(c.y) * dv);
        c.z = f2bf(bf2f(c.z) * dv); c.w = f2bf(bf2f(c.w) * dv);
        p[0] = a; p[1] = c;
    }
}

// ---- deep-unrolled 64-edge gather: all 16 row-loads in flight --------------
// SAFETY: lanes beyond the row (lane >= m) read uninitialized adj slots, so
// their offset VALUE is forced to 0 (a valid hs row); adds stay guarded.
#define GATHER64(PAYLOAD)                                                     \
    {                                                                         \
        int idx = beg + base + lane;                                          \
        int myoff = (lane < m) ? (adj[idx] << 6) : 0;                         \
        ushort4 u[16];                                                        \
        _Pragma("unroll")                                                     \
        for (int i = 0; i < 16; i++) {                                        \
            if (i * 4 < m) {                                                  \
                int o = __shfl(myoff, i * 4 + grp);                           \
                u[i] = *(const ushort4*)&PAYLOAD[(size_t)o + p4];             \
            }                                                                 \
        }                                                                     \
        _Pragma("unroll")                                                     \
        for (int i = 0; i < 16; i++) {                                        \
            if (i * 4 + grp < m) {                                            \
                acc.x += bf2f(u[i].x); acc.y += bf2f(u[i].y);                 \
                acc.z += bf2f(u[i].z); acc.w += bf2f(u[i].w);                 \
            }                                                                 \
        }                                                                     \
    }

// ---- layer 1 aggregate fused with TILED layer-2 GEMM -----------------------
// Block = 64 nodes, 512 threads (8 waves x 8 rounds of gathers).
// h1 rows kept f32 in LDS Htm[m][F1+4]; then tiled MM -> hs2 (bf16, *dinv).
__global__ __launch_bounds__(512) void k_agg1mm2(
    const int2* __restrict__ rowinfo, const int* __restrict__ adj,
    const unsigned short* __restrict__ hs, const float* __restrict__ dinv,
    const float* __restrict__ b1, const float* __restrict__ W2,
    unsigned short* __restrict__ hs2, int n, int AT) {
    __shared__ float W2s[F1 * FP];       // 16 KB [k][c], cols 41..63 = 0
    __shared__ float Htm[AMT][F1 + 4];   // 17 KB [m][k], pad 4
    int tid  = threadIdx.x;
    int w    = tid >> 6;                 // 8 waves
    int lane = tid & 63;
    int grp  = lane >> 4;
    int p4   = (lane & 15) * 4;
    int n0   = blockIdx.x * AMT;
    // stage W2 (f32); visibility covered by the barrier below
    for (int idx = tid; idx < F1 * FP; idx += 512) {
        int k = idx >> 6, c = idx & 63;
        W2s[idx] = (c < F2) ? W2[k * F2 + c] : 0.f;
    }
    // ---- gather phase: 8 rounds, wave w does node n0 + r*8 + w ------------
    for (int r = 0; r < 8; r++) {
        int nl   = r * 8 + w;
        int node = n0 + nl;
        float4 acc = {0.f, 0.f, 0.f, 0.f};
        if (node < n) {
            int2 ri = rowinfo[node];
            int beg = ri.x, deg = ri.y;
            if (grp == 0) {              // self-loop (pre-scaled)
                ushort4 u = *(const ushort4*)&hs[((size_t)node << 6) + p4];
                acc.x = bf2f(u.x); acc.y = bf2f(u.y);
                acc.z = bf2f(u.z); acc.w = bf2f(u.w);
            }
            for (int base = 0; base < deg; base += 64) {
                int m = deg - base; if (m > 64) m = 64;
                GATHER64(hs)
            }
            acc.x += __shfl_xor(acc.x, 16); acc.y += __shfl_xor(acc.y, 16);
            acc.z += __shfl_xor(acc.z, 16); acc.w += __shfl_xor(acc.w, 16);
            acc.x += __shfl_xor(acc.x, 32); acc.y += __shfl_xor(acc.y, 32);
            acc.z += __shfl_xor(acc.z, 32); acc.w += __shfl_xor(acc.w, 32);
        }
        if (grp == 0) {
            float4 v = {0.f, 0.f, 0.f, 0.f};
            if (node < n) {
                float dvn = dinv[node];
                float4 bg = *(const float4*)&b1[p4];
                v.x = acc.x * dvn + bg.x; v.x = v.x > 0.f ? v.x : 0.f;
                v.y = acc.y * dvn + bg.y; v.y = v.y > 0.f ? v.y : 0.f;
                v.z = acc.z * dvn + bg.z; v.z = v.z > 0.f ? v.z : 0.f;
                v.w = acc.w * dvn + bg.w; v.w = v.w > 0.f ? v.w : 0.f;
            }
            *(float4*)&Htm[nl][p4] = v;   // lane l -> cols 4l..4l+3: 2-way, free
        }
    }
    __syncthreads();
    // ---- mm2 phase (tiled, 256 threads): thread = rows {ml+16i} x 4 cols --
    if (tid < 256) {
        int ml = tid & 15;
        int c0 = (tid >> 4) * 4;
        float4 r0 = {0.f,0.f,0.f,0.f}, r1 = {0.f,0.f,0.f,0.f};
        float4 r2 = {0.f,0.f,0.f,0.f}, r3 = {0.f,0.f,0.f,0.f};
#pragma unroll
        for (int k = 0; k < F1; k += 4) {
            float4 w0 = *(const float4*)&W2s[(k + 0) * FP + c0];
            float4 w1 = *(const float4*)&W2s[(k + 1) * FP + c0];
            float4 w2 = *(const float4*)&W2s[(k + 2) * FP + c0];
            float4 w3 = *(const float4*)&W2s[(k + 3) * FP + c0];
            float4 a0 = *(const float4*)&Htm[ml     ][k];
            float4 a1 = *(const float4*)&Htm[ml + 16][k];
            float4 a2 = *(const float4*)&Htm[ml + 32][k];
            float4 a3 = *(const float4*)&Htm[ml + 48][k];
#define ACC4(r, a)                                                            \
            r.x += a.x*w0.x + a.y*w1.x + a.z*w2.x + a.w*w3.x;                 \
            r.y += a.x*w0.y + a.y*w1.y + a.z*w2.y + a.w*w3.y;                 \
            r.z += a.x*w0.z + a.y*w1.z + a.z*w2.z + a.w*w3.z;                 \
            r.w += a.x*w0.w + a.y*w1.w + a.z*w2.w + a.w*w3.w;
            ACC4(r0, a0) ACC4(r1, a1) ACC4(r2, a2) ACC4(r3, a3)
#undef ACC4
        }
        float4 rr[4] = {r0, r1, r2, r3};
#pragma unroll
        for (int i = 0; i < 4; i++) {
            int node = n0 + ml + 16 * i;
            if (node < n) {
                float dv = dinv[node];
                ushort4 o = { f2bf(rr[i].x * dv), f2bf(rr[i].y * dv),
                              f2bf(rr[i].z * dv), f2bf(rr[i].w * dv) };
                *(ushort4*)&hs2[((size_t)node << 6) + c0] = o;
            }
        }
    }
}

// ---- layer 2 aggregate: out = dinv*(gather+self) + b2 ----------------------
__global__ __launch_bounds__(256) void k_agg2(
    const int2* __restrict__ rowinfo, const int* __restrict__ adj,
    const unsigned short* __restrict__ hs2, const float* __restrict__ dinv,
    const float* __restrict__ b2, float* __restrict__ out, int n, int AT) {
    int node = blockIdx.x * 4 + (threadIdx.x >> 6);
    if (node >= n) return;
    int lane = threadIdx.x & 63;
    int grp  = lane >> 4;
    int p4   = (lane & 15) * 4;
    int2 ri = rowinfo[node];
    int beg = ri.x, deg = ri.y;
    float4 acc = {0.f, 0.f, 0.f, 0.f};
    if (grp == 0) {
        ushort4 u = *(const ushort4*)&hs2[((size_t)node << 6) + p4];
        acc.x = bf2f(u.x); acc.y = bf2f(u.y); acc.z = bf2f(u.z); acc.w = bf2f(u.w);
    }
    for (int base = 0; base < deg; base += 64) {
        int m = deg - base; if (m > 64) m = 64;
        GATHER64(hs2)
    }
    acc.x += __shfl_xor(acc.x, 16); acc.y += __shfl_xor(acc.y, 16);
    acc.z += __shfl_xor(acc.z, 16); acc.w += __shfl_xor(acc.w, 16);
    acc.x += __shfl_xor(acc.x, 32); acc.y += __shfl_xor(acc.y, 32);
    acc.z += __shfl_xor(acc.z, 32); acc.w += __shfl_xor(acc.w, 32);
    if (grp == 0) {
        float dv = dinv[node];
        float vv[4] = {acc.x, acc.y, acc.z, acc.w};
#pragma unroll
        for (int j = 0; j < 4; j++) {
            int f = p4 + j;
            if (f < F2) out[(size_t)node * F2 + f] = vv[j] * dv + b2[f];
        }
    }
}

extern "C" void kernel_launch(void* const* d_in, const int* in_sizes, int n_in,
                              void* d_out, int out_size, void* d_ws, size_t ws_size,
                              hipStream_t stream) {
    const float* x  = (const float*)d_in[0];
    const int*   ei = (const int*)d_in[1];
    const float* W1 = (const float*)d_in[2];
    const float* b1 = (const float*)d_in[3];
    const float* W2 = (const float*)d_in[4];
    const float* b2 = (const float*)d_in[5];
    float* out = (float*)d_out;

    const int n = in_sizes[0] / FIN;   // 100000
    const int E = in_sizes[1] / 2;     // 1600000
    const int* src = ei;
    const int* dst = ei + E;
    const int nbuck   = (n + 255) >> BSH;              // 391
    const int nchunks = (E + CHUNK_P - 1) / CHUNK_P;   // 391
    const int nmm     = (n + MT - 1) / MT;             // 782
    const int nagg1   = (n + AMT - 1) / AMT;           // 1563
    const int nagg    = (n + 3) / 4;                   // 25000
    const int adjtot  = nbuck * BCAP;

    char* ws = (char*)d_ws;
    size_t off = 0;
    auto alloc = [&](size_t bytes) {
        void* p = ws + off;
        off = (off + bytes + 511) & ~(size_t)511;
        return p;
    };
    unsigned short* offs = (unsigned short*)alloc((size_t)nchunks * (nbuck + 1) * 2);
    int*   pairs   = (int*)alloc((size_t)nchunks * CHUNK_P * 4); // 6.4 MB
    int*   adj     = (int*)alloc((size_t)adjtot * 4 + 256);      // 9.6 MB
    int2*  rowinfo = (int2*)alloc((size_t)n * 8);
    float* dinv    = (float*)alloc((size_t)n * 4);
    unsigned short* hs1 = (unsigned short*)alloc((size_t)n * FP * 2);
    unsigned short* hs2 = (unsigned short*)alloc((size_t)n * FP * 2);

    k_partmm1<<<nchunks + nmm, 256, 0, stream>>>(src, dst, offs, pairs, E, nchunks,
                                                 nbuck, x, W1, hs1, n);
    k_build<<<nbuck, 1024, 0, stream>>>(offs, pairs, nchunks, nbuck, adj, rowinfo,
                                        dinv, hs1, n);
    k_agg1mm2<<<nagg1, 512, 0, stream>>>(rowinfo, adj, hs1, dinv, b1, W2, hs2,
                                         n, adjtot);
    k_agg2<<<nagg, 256, 0, stream>>>(rowinfo, adj, hs2, dinv, b2, out, n, adjtot);
}

// Round 7
// 706.709 us; speedup vs baseline: 1.0156x; 1.0156x over previous
//
#include <hip/hip_runtime.h>

// GCN 2-layer forward. CSR-gather, bf16 payloads (stride-64, 128 B rows).
// Pipeline (4 dispatches):
//   partmm1 (edge partition + hs1 = bf16(x@W1))
//   build   (1024-thr wave-parallel CSR build + hs1 *= dinv)
//   agg1mm2 (64-node blocks: gather h1 -> f32 LDS, then TILED h1@W2 -> hs2)
//   agg2    (out = dinv*gather + b2)
//
// R7 = R6 spill fix. R6's conditionally-assigned ushort4 u[16] was demoted
// to scratch (VGPR 128, WRITE_SIZE 12.5->550 MB, occupancy 14%, 546us).
// Fix: ALL 16 loads unconditional (lanes >= m use sanitized offset 0 = valid
// row; wasted loads are L1-hits on one 128B row), only the accumulate is
// guarded. Unconditional defs -> clean SSA -> registers.

#define FIN 128
#define F1  64
#define F2  41
#define FP  64     // payload row stride (bf16 elems): 128 B, 2 lines, aligned

#define BSH    8                 // bucket = dst >> 8 (256 nodes/bucket)
#define BCAP   6144              // per-bucket adj window (mean 4096, >30 sigma)
#define CHUNK_P 4096             // edges per part block (16/thread)

#define MT 128                   // mm1 GEMM M-tile
#define KC 16                    // mm1 GEMM K-chunk
#define AMT 64                   // agg1mm2 nodes per block

#define SMEM_BYTES 24576         // union: part 19.5 KB / mm1 24.6 KB -> 6 blk/CU

__device__ __forceinline__ unsigned short f2bf(float f) {
    unsigned u = __builtin_bit_cast(unsigned, f);
    u += 0x7FFFu + ((u >> 16) & 1u);           // RNE
    return (unsigned short)(u >> 16);
}
__device__ __forceinline__ float bf2f(unsigned short h) {
    unsigned u = ((unsigned)h) << 16;
    return __builtin_bit_cast(float, u);
}

// ---- fused: blocks [0,nchunks) = edge partition; rest = layer-1 GEMM -------
__global__ __launch_bounds__(256) void k_partmm1(
    const int* __restrict__ src, const int* __restrict__ dst,
    unsigned short* __restrict__ offs, int* __restrict__ pairs,
    int E, int nchunks, int NB,
    const float* __restrict__ x, const float* __restrict__ W1,
    unsigned short* __restrict__ hs, int n) {
    __shared__ alignas(16) char smem[SMEM_BYTES];
    int tid = threadIdx.x;
    if ((int)blockIdx.x < nchunks) {
        // ---------------- PART (19.5 KB): LDS bucket-sort, coalesced out ----
        int* hist = (int*)smem;            // 512 ints (2 KB)
        int* lex  = hist + 512;            // 256 (1 KB)
        int* limg = lex + 256;             // CHUNK_P ints (16 KB)
        int e0  = blockIdx.x * CHUNK_P;
        int ds[CHUNK_P / 256], ss[CHUNK_P / 256];
#pragma unroll
        for (int j = 0; j < CHUNK_P / 256; j++) {
            int e = e0 + j * 256 + tid;
            if (e < E) { ds[j] = dst[e]; ss[j] = src[e]; } else ds[j] = -1;
        }
        hist[tid] = 0; hist[tid + 256] = 0;
        __syncthreads();
#pragma unroll
        for (int j = 0; j < CHUNK_P / 256; j++)
            if (ds[j] >= 0) atomicAdd(&hist[ds[j] >> BSH], 1);
        __syncthreads();
        int b0 = 2 * tid, b1 = 2 * tid + 1;
        int c0 = hist[b0], c1 = hist[b1];
        int s  = c0 + c1;
        lex[tid] = s;
        __syncthreads();
        for (int off = 1; off < 256; off <<= 1) {
            int v = lex[tid];
            int a = (tid >= off) ? lex[tid - off] : 0;
            __syncthreads();
            lex[tid] = v + a;
            __syncthreads();
        }
        int incl = lex[tid];
        int ex0 = incl - s;
        int ex1 = ex0 + c0;
        // per-chunk bucket offset row (u16): starts[b], plus total at [NB]
        unsigned short* orow = offs + (size_t)blockIdx.x * (NB + 1);
        if (b0 < NB) orow[b0] = (unsigned short)ex0;
        if (b1 < NB) orow[b1] = (unsigned short)ex1;
        if (tid == 255) orow[NB] = (unsigned short)incl;
        hist[b0] = ex0; hist[b1] = ex1;
        __syncthreads();
#pragma unroll
        for (int j = 0; j < CHUNK_P / 256; j++) {
            if (ds[j] >= 0) {
                int b = ds[j] >> BSH;
                int p = atomicAdd(&hist[b], 1);
                limg[p] = (ss[j] << BSH) | (ds[j] & 255);
            }
        }
        __syncthreads();
        int tot = lex[255];
        int* pout = pairs + (size_t)blockIdx.x * CHUNK_P;
        for (int k = tid; k < tot; k += 256)   // fully coalesced
            pout[k] = limg[k];
    } else {
        // ---------------- MM1: hs1 = bf16(x @ W1), UNSCALED (24.6 KB) -------
        unsigned short* Ws = (unsigned short*)smem;      // 16 KB, W1 as bf16
        float (*As)[MT] = (float(*)[MT])(smem + FIN * F1 * 2);  // 8 KB
        int n0 = ((int)blockIdx.x - nchunks) * MT;
#pragma unroll
        for (int j = 0; j < 8; j++) {
            int f = j * 256 + tid;                       // float4 index (2048)
            float4 w4 = ((const float4*)W1)[f];
            ushort4 o = { f2bf(w4.x), f2bf(w4.y), f2bf(w4.z), f2bf(w4.w) };
            ((ushort4*)Ws)[f] = o;
        }
        int m0 = (tid & 15) * 8;
        int c0 = (tid >> 4) * 4;
        int m_l = tid & 127;
        int kh  = (tid >> 7) * 8;
        bool mvalid = (n0 + m_l) < n;
        const float* xrow = x + (size_t)(n0 + m_l) * FIN + kh;
        float acc[8][4] = {};
        for (int kc = 0; kc < FIN; kc += KC) {
            __syncthreads();
            float4 v0 = mvalid ? *(const float4*)(xrow + kc)     : float4{0.f,0.f,0.f,0.f};
            float4 v1 = mvalid ? *(const float4*)(xrow + kc + 4) : float4{0.f,0.f,0.f,0.f};
            As[kh + 0][m_l] = v0.x; As[kh + 1][m_l] = v0.y;
            As[kh + 2][m_l] = v0.z; As[kh + 3][m_l] = v0.w;
            As[kh + 4][m_l] = v1.x; As[kh + 5][m_l] = v1.y;
            As[kh + 6][m_l] = v1.z; As[kh + 7][m_l] = v1.w;
            __syncthreads();
#pragma unroll
            for (int k = 0; k < KC; k++) {
                float4 a0 = *(const float4*)&As[k][m0];
                float4 a1 = *(const float4*)&As[k][m0 + 4];
                ushort4 wq = *(const ushort4*)&Ws[(kc + k) * F1 + c0];
                float wx = bf2f(wq.x), wy = bf2f(wq.y);
                float wz = bf2f(wq.z), ww = bf2f(wq.w);
                float a[8] = {a0.x, a0.y, a0.z, a0.w, a1.x, a1.y, a1.z, a1.w};
#pragma unroll
                for (int i = 0; i < 8; i++) {
                    acc[i][0] += a[i] * wx;
                    acc[i][1] += a[i] * wy;
                    acc[i][2] += a[i] * wz;
                    acc[i][3] += a[i] * ww;
                }
            }
        }
#pragma unroll
        for (int i = 0; i < 8; i++) {
            int node = n0 + m0 + i;
            if (node < n) {
                ushort4 o = { f2bf(acc[i][0]), f2bf(acc[i][1]),
                              f2bf(acc[i][2]), f2bf(acc[i][3]) };
                *(ushort4*)&hs[((size_t)node << 6) + c0] = o;
            }
        }
    }
}

// ---- pass 2: wave-parallel per-bucket CSR build + tail-scale hs1 -----------
__global__ __launch_bounds__(1024) void k_build(
    const unsigned short* __restrict__ offs, const int* __restrict__ pairs,
    int nchunks, int NB, int* __restrict__ adj,
    int2* __restrict__ rowinfo, float* __restrict__ dinv,
    unsigned short* __restrict__ hs1, int n) {
    __shared__ int lcnt[256];
    __shared__ int lex[256];
    __shared__ int lcur[256];
    __shared__ float ldv[256];
    int tid  = threadIdx.x;
    int wave = tid >> 6;               // 16 waves
    int lane = tid & 63;
    int b    = blockIdx.x;
    int NB1  = NB + 1;
    int node0 = b << BSH;
    int base  = b * BCAP;              // static adj window

    if (tid < 256) lcnt[tid] = 0;
    __syncthreads();
    // pass 1: per-node histogram; each wave sweeps whole segments
    for (int c = wave; c < nchunks; c += 16) {
        int s0 = offs[(size_t)c * NB1 + b];
        int s1 = offs[(size_t)c * NB1 + b + 1];
        const int* pc = pairs + (size_t)c * CHUNK_P;
        for (int i = s0 + lane; i < s1; i += 64)
            atomicAdd(&lcnt[pc[i] & 255], 1);
    }
    __syncthreads();
    int own = (tid < 256) ? lcnt[tid] : 0;
    if (tid < 256) lex[tid] = own;
    __syncthreads();
    for (int off = 1; off < 256; off <<= 1) {
        int val = 0, add = 0;
        if (tid < 256) {
            val = lex[tid];
            add = (tid >= off) ? lex[tid - off] : 0;
        }
        __syncthreads();
        if (tid < 256) lex[tid] = val + add;
        __syncthreads();
    }
    int excl = (tid < 256) ? (lex[tid] - own) : 0;
    float dvn = rsqrtf((float)own + 1.0f);
    if (tid < 256) { lcur[tid] = excl; ldv[tid] = dvn; }
    __syncthreads();
    // pass 2: place src ids into the adj window, wave-parallel
    for (int c = wave; c < nchunks; c += 16) {
        int s0 = offs[(size_t)c * NB1 + b];
        int s1 = offs[(size_t)c * NB1 + b + 1];
        const int* pc = pairs + (size_t)c * CHUNK_P;
        for (int i = s0 + lane; i < s1; i += 64) {
            int pk  = pc[i];
            int pos = atomicAdd(&lcur[pk & 255], 1);
            adj[base + pos] = pk >> BSH;
        }
    }
    int node = node0 + tid;
    if (tid < 256 && node < n) {
        rowinfo[node] = make_int2(base + excl, own);
        dinv[node]    = dvn;
    }
    // ---- tail: hs1[node] *= dinv[node] for this bucket's 256 nodes --------
    for (int u = tid; u < 2048; u += 1024) {
        int nd = node0 + (u >> 3);
        if (nd >= n) break;
        float dv = ldv[u >> 3];
        ushort4* p = (ushort4*)&hs1[((size_t)nd << 6) + (u & 7) * 8];
        ushort4 a = p[0], c = p[1];
        a.x = f2bf(bf2f(a.x) * dv); a.y = f2bf(bf2f(a.y) * dv);
        a.z = f2bf(bf2f(a.z) * dv); a.w = f2bf(bf2f(a.w) * dv);
        c.x = f2bf(bf2f(c.x) * dv); c.y = f2bf(bf2f(c.y) * dv);
        c.z = f2bf(bf2f(c.z) * dv); c.w = f2bf(bf2f(c.w) * dv);
        p[0] = a; p[1] = c;
    }
}

// ---- deep-unrolled 64-edge gather: all 16 row-loads UNCONDITIONAL ----------
// Lanes >= m have offset sanitized to 0 (valid row); loads always issue
// (clean SSA -> registers, no scratch). Only the accumulate is guarded.
#define GATHER64(PAYLOAD)                                                     \
    {                                                                         \
        int idx = beg + base + lane;                                          \
        int av = adj[idx < AT ? idx : 0];                                     \
        int myoff = (lane < m) ? (av << 6) : 0;                               \
        ushort4 u[16];                                                        \
        _Pragma("unroll")                                                     \
        for (int i = 0; i < 16; i++) {                                        \
            int o = __shfl(myoff, i * 4 + grp);                               \
            u[i] = *(const ushort4*)&PAYLOAD[(size_t)o + p4];                 \
        }                                                                     \
        _Pragma("unroll")                                                     \
        for (int i = 0; i < 16; i++) {                                        \
            if (i * 4 + grp < m) {                                            \
                acc.x += bf2f(u[i].x); acc.y += bf2f(u[i].y);                 \
                acc.z += bf2f(u[i].z); acc.w += bf2f(u[i].w);                 \
            }                                                                 \
        }                                                                     \
    }

// ---- layer 1 aggregate fused with TILED layer-2 GEMM -----------------------
// Block = 64 nodes, 512 threads (8 waves x 8 rounds of gathers).
// h1 rows kept f32 in LDS Htm[m][F1+4]; then tiled MM -> hs2 (bf16, *dinv).
__global__ __launch_bounds__(512) void k_agg1mm2(
    const int2* __restrict__ rowinfo, const int* __restrict__ adj,
    const unsigned short* __restrict__ hs, const float* __restrict__ dinv,
    const float* __restrict__ b1, const float* __restrict__ W2,
    unsigned short* __restrict__ hs2, int n, int AT) {
    __shared__ float W2s[F1 * FP];       // 16 KB [k][c], cols 41..63 = 0
    __shared__ float Htm[AMT][F1 + 4];   // 17 KB [m][k], pad 4
    int tid  = threadIdx.x;
    int w    = tid >> 6;                 // 8 waves
    int lane = tid & 63;
    int grp  = lane >> 4;
    int p4   = (lane & 15) * 4;
    int n0   = blockIdx.x * AMT;
    // stage W2 (f32); visibility covered by the barrier below
    for (int idx = tid; idx < F1 * FP; idx += 512) {
        int k = idx >> 6, c = idx & 63;
        W2s[idx] = (c < F2) ? W2[k * F2 + c] : 0.f;
    }
    // ---- gather phase: 8 rounds, wave w does node n0 + r*8 + w ------------
    for (int r = 0; r < 8; r++) {
        int nl   = r * 8 + w;
        int node = n0 + nl;
        float4 acc = {0.f, 0.f, 0.f, 0.f};
        if (node < n) {
            int2 ri = rowinfo[node];
            int beg = ri.x, deg = ri.y;
            if (grp == 0) {              // self-loop (pre-scaled)
                ushort4 u = *(const ushort4*)&hs[((size_t)node << 6) + p4];
                acc.x = bf2f(u.x); acc.y = bf2f(u.y);
                acc.z = bf2f(u.z); acc.w = bf2f(u.w);
            }
            for (int base = 0; base < deg; base += 64) {
                int m = deg - base; if (m > 64) m = 64;
                GATHER64(hs)
            }
            acc.x += __shfl_xor(acc.x, 16); acc.y += __shfl_xor(acc.y, 16);
            acc.z += __shfl_xor(acc.z, 16); acc.w += __shfl_xor(acc.w, 16);
            acc.x += __shfl_xor(acc.x, 32); acc.y += __shfl_xor(acc.y, 32);
            acc.z += __shfl_xor(acc.z, 32); acc.w += __shfl_xor(acc.w, 32);
        }
        if (grp == 0) {
            float4 v = {0.f, 0.f, 0.f, 0.f};
            if (node < n) {
                float dvn = dinv[node];
                float4 bg = *(const float4*)&b1[p4];
                v.x = acc.x * dvn + bg.x; v.x = v.x > 0.f ? v.x : 0.f;
                v.y = acc.y * dvn + bg.y; v.y = v.y > 0.f ? v.y : 0.f;
                v.z = acc.z * dvn + bg.z; v.z = v.z > 0.f ? v.z : 0.f;
                v.w = acc.w * dvn + bg.w; v.w = v.w > 0.f ? v.w : 0.f;
            }
            *(float4*)&Htm[nl][p4] = v;   // lane l -> cols 4l..4l+3: 2-way, free
        }
    }
    __syncthreads();
    // ---- mm2 phase (tiled, 256 threads): thread = rows {ml+16i} x 4 cols --
    if (tid < 256) {
        int ml = tid & 15;
        int c0 = (tid >> 4) * 4;
        float4 r0 = {0.f,0.f,0.f,0.f}, r1 = {0.f,0.f,0.f,0.f};
        float4 r2 = {0.f,0.f,0.f,0.f}, r3 = {0.f,0.f,0.f,0.f};
#pragma unroll
        for (int k = 0; k < F1; k += 4) {
            float4 w0 = *(const float4*)&W2s[(k + 0) * FP + c0];
            float4 w1 = *(const float4*)&W2s[(k + 1) * FP + c0];
            float4 w2 = *(const float4*)&W2s[(k + 2) * FP + c0];
            float4 w3 = *(const float4*)&W2s[(k + 3) * FP + c0];
            float4 a0 = *(const float4*)&Htm[ml     ][k];
            float4 a1 = *(const float4*)&Htm[ml + 16][k];
            float4 a2 = *(const float4*)&Htm[ml + 32][k];
            float4 a3 = *(const float4*)&Htm[ml + 48][k];
#define ACC4(r, a)                                                            \
            r.x += a.x*w0.x + a.y*w1.x + a.z*w2.x + a.w*w3.x;                 \
            r.y += a.x*w0.y + a.y*w1.y + a.z*w2.y + a.w*w3.y;                 \
            r.z += a.x*w0.z + a.y*w1.z + a.z*w2.z + a.w*w3.z;                 \
            r.w += a.x*w0.w + a.y*w1.w + a.z*w2.w + a.w*w3.w;
            ACC4(r0, a0) ACC4(r1, a1) ACC4(r2, a2) ACC4(r3, a3)
#undef ACC4
        }
        float4 rr[4] = {r0, r1, r2, r3};
#pragma unroll
        for (int i = 0; i < 4; i++) {
            int node = n0 + ml + 16 * i;
            if (node < n) {
                float dv = dinv[node];
                ushort4 o = { f2bf(rr[i].x * dv), f2bf(rr[i].y * dv),
                              f2bf(rr[i].z * dv), f2bf(rr[i].w * dv) };
                *(ushort4*)&hs2[((size_t)node << 6) + c0] = o;
            }
        }
    }
}

// ---- layer 2 aggregate: out = dinv*(gather+self) + b2 ----------------------
__global__ __launch_bounds__(256) void k_agg2(
    const int2* __restrict__ rowinfo, const int* __restrict__ adj,
    const unsigned short* __restrict__ hs2, const float* __restrict__ dinv,
    const float* __restrict__ b2, float* __restrict__ out, int n, int AT) {
    int node = blockIdx.x * 4 + (threadIdx.x >> 6);
    if (node >= n) return;
    int lane = threadIdx.x & 63;
    int grp  = lane >> 4;
    int p4   = (lane & 15) * 4;
    int2 ri = rowinfo[node];
    int beg = ri.x, deg = ri.y;
    float4 acc = {0.f, 0.f, 0.f, 0.f};
    if (grp == 0) {
        ushort4 u = *(const ushort4*)&hs2[((size_t)node << 6) + p4];
        acc.x = bf2f(u.x); acc.y = bf2f(u.y); acc.z = bf2f(u.z); acc.w = bf2f(u.w);
    }
    for (int base = 0; base < deg; base += 64) {
        int m = deg - base; if (m > 64) m = 64;
        GATHER64(hs2)
    }
    acc.x += __shfl_xor(acc.x, 16); acc.y += __shfl_xor(acc.y, 16);
    acc.z += __shfl_xor(acc.z, 16); acc.w += __shfl_xor(acc.w, 16);
    acc.x += __shfl_xor(acc.x, 32); acc.y += __shfl_xor(acc.y, 32);
    acc.z += __shfl_xor(acc.z, 32); acc.w += __shfl_xor(acc.w, 32);
    if (grp == 0) {
        float dv = dinv[node];
        float vv[4] = {acc.x, acc.y, acc.z, acc.w};
#pragma unroll
        for (int j = 0; j < 4; j++) {
            int f = p4 + j;
            if (f < F2) out[(size_t)node * F2 + f] = vv[j] * dv + b2[f];
        }
    }
}

extern "C" void kernel_launch(void* const* d_in, const int* in_sizes, int n_in,
                              void* d_out, int out_size, void* d_ws, size_t ws_size,
                              hipStream_t stream) {
    const float* x  = (const float*)d_in[0];
    const int*   ei = (const int*)d_in[1];
    const float* W1 = (const float*)d_in[2];
    const float* b1 = (const float*)d_in[3];
    const float* W2 = (const float*)d_in[4];
    const float* b2 = (const float*)d_in[5];
    float* out = (float*)d_out;

    const int n = in_sizes[0] / FIN;   // 100000
    const int E = in_sizes[1] / 2;     // 1600000
    const int* src = ei;
    const int* dst = ei + E;
    const int nbuck   = (n + 255) >> BSH;              // 391
    const int nchunks = (E + CHUNK_P - 1) / CHUNK_P;   // 391
    const int nmm     = (n + MT - 1) / MT;             // 782
    const int nagg1   = (n + AMT - 1) / AMT;           // 1563
    const int nagg    = (n + 3) / 4;                   // 25000
    const int adjtot  = nbuck * BCAP;

    char* ws = (char*)d_ws;
    size_t off = 0;
    auto alloc = [&](size_t bytes) {
        void* p = ws + off;
        off = (off + bytes + 511) & ~(size_t)511;
        return p;
    };
    unsigned short* offs = (unsigned short*)alloc((size_t)nchunks * (nbuck + 1) * 2);
    int*   pairs   = (int*)alloc((size_t)nchunks * CHUNK_P * 4); // 6.4 MB
    int*   adj     = (int*)alloc((size_t)adjtot * 4 + 256);      // 9.6 MB
    int2*  rowinfo = (int2*)alloc((size_t)n * 8);
    float* dinv    = (float*)alloc((size_t)n * 4);
    unsigned short* hs1 = (unsigned short*)alloc((size_t)n * FP * 2);
    unsigned short* hs2 = (unsigned short*)alloc((size_t)n * FP * 2);

    k_partmm1<<<nchunks + nmm, 256, 0, stream>>>(src, dst, offs, pairs, E, nchunks,
                                                 nbuck, x, W1, hs1, n);
    k_build<<<nbuck, 1024, 0, stream>>>(offs, pairs, nchunks, nbuck, adj, rowinfo,
                                        dinv, hs1, n);
    k_agg1mm2<<<nagg1, 512, 0, stream>>>(rowinfo, adj, hs1, dinv, b1, W2, hs2,
                                         n, adjtot);
    k_agg2<<<nagg, 256, 0, stream>>>(rowinfo, adj, hs2, dinv, b2, out, n, adjtot);
}

// Round 8
// 659.749 us; speedup vs baseline: 1.0879x; 1.0712x over previous
//
#include <hip/hip_runtime.h>

// GCN 2-layer forward. CSR-gather, bf16 payloads (stride-64, 128 B rows).
// Pipeline (4 dispatches):
//   partmm1 (edge partition + hs1 = bf16(x@W1))
//   build   (1024-thr wave-parallel CSR build + hs1 *= dinv)
//   agg1mm2 (64-node blocks: gather h1 -> f32 LDS, then TILED h1@W2 -> hs2)
//   agg2    (32-node blocks: out = dinv*gather + b2)
//
// R8: consolidation. R5-R7's regression was `ushort4 u[16]` ARRAY in a macro
// -> unroll pragma failed -> runtime-indexed -> scratch (VGPR 128, 556 MB
// scratch writes). Reverted to R4's proven named-variable 16-edge gather
// (16 rows/wave in flight — already deep enough for mean deg 16). Kept from
// R6: transposed Htm[m][F1+4] (h1 store contiguous float4/lane, conflict-free;
// was 8-way, 2.8M conflicts). New: node-level prefetch of rowinfo/dinv for
// round r+1 (hides one of the 3 serial memory hops per node); agg2 uses the
// same 8-rounds-per-wave shape.

#define FIN 128
#define F1  64
#define F2  41
#define FP  64     // payload row stride (bf16 elems): 128 B, 2 lines, aligned

#define BSH    8                 // bucket = dst >> 8 (256 nodes/bucket)
#define BCAP   6144              // per-bucket adj window (mean 4096, >30 sigma)
#define CHUNK_P 4096             // edges per part block (16/thread)

#define MT 128                   // mm1 GEMM M-tile
#define KC 16                    // mm1 GEMM K-chunk
#define AMT 64                   // agg1mm2 nodes per block

#define SMEM_BYTES 24576         // union: part 19.5 KB / mm1 24.6 KB -> 6 blk/CU

__device__ __forceinline__ unsigned short f2bf(float f) {
    unsigned u = __builtin_bit_cast(unsigned, f);
    u += 0x7FFFu + ((u >> 16) & 1u);           // RNE
    return (unsigned short)(u >> 16);
}
__device__ __forceinline__ float bf2f(unsigned short h) {
    unsigned u = ((unsigned)h) << 16;
    return __builtin_bit_cast(float, u);
}

// ---- fused: blocks [0,nchunks) = edge partition; rest = layer-1 GEMM -------
__global__ __launch_bounds__(256) void k_partmm1(
    const int* __restrict__ src, const int* __restrict__ dst,
    unsigned short* __restrict__ offs, int* __restrict__ pairs,
    int E, int nchunks, int NB,
    const float* __restrict__ x, const float* __restrict__ W1,
    unsigned short* __restrict__ hs, int n) {
    __shared__ alignas(16) char smem[SMEM_BYTES];
    int tid = threadIdx.x;
    if ((int)blockIdx.x < nchunks) {
        // ---------------- PART (19.5 KB): LDS bucket-sort, coalesced out ----
        int* hist = (int*)smem;            // 512 ints (2 KB)
        int* lex  = hist + 512;            // 256 (1 KB)
        int* limg = lex + 256;             // CHUNK_P ints (16 KB)
        int e0  = blockIdx.x * CHUNK_P;
        int ds[CHUNK_P / 256], ss[CHUNK_P / 256];
#pragma unroll
        for (int j = 0; j < CHUNK_P / 256; j++) {
            int e = e0 + j * 256 + tid;
            if (e < E) { ds[j] = dst[e]; ss[j] = src[e]; } else ds[j] = -1;
        }
        hist[tid] = 0; hist[tid + 256] = 0;
        __syncthreads();
#pragma unroll
        for (int j = 0; j < CHUNK_P / 256; j++)
            if (ds[j] >= 0) atomicAdd(&hist[ds[j] >> BSH], 1);
        __syncthreads();
        int b0 = 2 * tid, b1 = 2 * tid + 1;
        int c0 = hist[b0], c1 = hist[b1];
        int s  = c0 + c1;
        lex[tid] = s;
        __syncthreads();
        for (int off = 1; off < 256; off <<= 1) {
            int v = lex[tid];
            int a = (tid >= off) ? lex[tid - off] : 0;
            __syncthreads();
            lex[tid] = v + a;
            __syncthreads();
        }
        int incl = lex[tid];
        int ex0 = incl - s;
        int ex1 = ex0 + c0;
        // per-chunk bucket offset row (u16): starts[b], plus total at [NB]
        unsigned short* orow = offs + (size_t)blockIdx.x * (NB + 1);
        if (b0 < NB) orow[b0] = (unsigned short)ex0;
        if (b1 < NB) orow[b1] = (unsigned short)ex1;
        if (tid == 255) orow[NB] = (unsigned short)incl;
        hist[b0] = ex0; hist[b1] = ex1;
        __syncthreads();
#pragma unroll
        for (int j = 0; j < CHUNK_P / 256; j++) {
            if (ds[j] >= 0) {
                int b = ds[j] >> BSH;
                int p = atomicAdd(&hist[b], 1);
                limg[p] = (ss[j] << BSH) | (ds[j] & 255);
            }
        }
        __syncthreads();
        int tot = lex[255];
        int* pout = pairs + (size_t)blockIdx.x * CHUNK_P;
        for (int k = tid; k < tot; k += 256)   // fully coalesced
            pout[k] = limg[k];
    } else {
        // ---------------- MM1: hs1 = bf16(x @ W1), UNSCALED (24.6 KB) -------
        unsigned short* Ws = (unsigned short*)smem;      // 16 KB, W1 as bf16
        float (*As)[MT] = (float(*)[MT])(smem + FIN * F1 * 2);  // 8 KB
        int n0 = ((int)blockIdx.x - nchunks) * MT;
#pragma unroll
        for (int j = 0; j < 8; j++) {
            int f = j * 256 + tid;                       // float4 index (2048)
            float4 w4 = ((const float4*)W1)[f];
            ushort4 o = { f2bf(w4.x), f2bf(w4.y), f2bf(w4.z), f2bf(w4.w) };
            ((ushort4*)Ws)[f] = o;
        }
        int m0 = (tid & 15) * 8;
        int c0 = (tid >> 4) * 4;
        int m_l = tid & 127;
        int kh  = (tid >> 7) * 8;
        bool mvalid = (n0 + m_l) < n;
        const float* xrow = x + (size_t)(n0 + m_l) * FIN + kh;
        float acc[8][4] = {};
        for (int kc = 0; kc < FIN; kc += KC) {
            __syncthreads();
            float4 v0 = mvalid ? *(const float4*)(xrow + kc)     : float4{0.f,0.f,0.f,0.f};
            float4 v1 = mvalid ? *(const float4*)(xrow + kc + 4) : float4{0.f,0.f,0.f,0.f};
            As[kh + 0][m_l] = v0.x; As[kh + 1][m_l] = v0.y;
            As[kh + 2][m_l] = v0.z; As[kh + 3][m_l] = v0.w;
            As[kh + 4][m_l] = v1.x; As[kh + 5][m_l] = v1.y;
            As[kh + 6][m_l] = v1.z; As[kh + 7][m_l] = v1.w;
            __syncthreads();
#pragma unroll
            for (int k = 0; k < KC; k++) {
                float4 a0 = *(const float4*)&As[k][m0];
                float4 a1 = *(const float4*)&As[k][m0 + 4];
                ushort4 wq = *(const ushort4*)&Ws[(kc + k) * F1 + c0];
                float wx = bf2f(wq.x), wy = bf2f(wq.y);
                float wz = bf2f(wq.z), ww = bf2f(wq.w);
                float a[8] = {a0.x, a0.y, a0.z, a0.w, a1.x, a1.y, a1.z, a1.w};
#pragma unroll
                for (int i = 0; i < 8; i++) {
                    acc[i][0] += a[i] * wx;
                    acc[i][1] += a[i] * wy;
                    acc[i][2] += a[i] * wz;
                    acc[i][3] += a[i] * ww;
                }
            }
        }
#pragma unroll
        for (int i = 0; i < 8; i++) {
            int node = n0 + m0 + i;
            if (node < n) {
                ushort4 o = { f2bf(acc[i][0]), f2bf(acc[i][1]),
                              f2bf(acc[i][2]), f2bf(acc[i][3]) };
                *(ushort4*)&hs[((size_t)node << 6) + c0] = o;
            }
        }
    }
}

// ---- pass 2: wave-parallel per-bucket CSR build + tail-scale hs1 -----------
__global__ __launch_bounds__(1024) void k_build(
    const unsigned short* __restrict__ offs, const int* __restrict__ pairs,
    int nchunks, int NB, int* __restrict__ adj,
    int2* __restrict__ rowinfo, float* __restrict__ dinv,
    unsigned short* __restrict__ hs1, int n) {
    __shared__ int lcnt[256];
    __shared__ int lex[256];
    __shared__ int lcur[256];
    __shared__ float ldv[256];
    int tid  = threadIdx.x;
    int wave = tid >> 6;               // 16 waves
    int lane = tid & 63;
    int b    = blockIdx.x;
    int NB1  = NB + 1;
    int node0 = b << BSH;
    int base  = b * BCAP;              // static adj window

    if (tid < 256) lcnt[tid] = 0;
    __syncthreads();
    // pass 1: per-node histogram; each wave sweeps whole segments
    for (int c = wave; c < nchunks; c += 16) {
        int s0 = offs[(size_t)c * NB1 + b];
        int s1 = offs[(size_t)c * NB1 + b + 1];
        const int* pc = pairs + (size_t)c * CHUNK_P;
        for (int i = s0 + lane; i < s1; i += 64)
            atomicAdd(&lcnt[pc[i] & 255], 1);
    }
    __syncthreads();
    int own = (tid < 256) ? lcnt[tid] : 0;
    if (tid < 256) lex[tid] = own;
    __syncthreads();
    for (int off = 1; off < 256; off <<= 1) {
        int val = 0, add = 0;
        if (tid < 256) {
            val = lex[tid];
            add = (tid >= off) ? lex[tid - off] : 0;
        }
        __syncthreads();
        if (tid < 256) lex[tid] = val + add;
        __syncthreads();
    }
    int excl = (tid < 256) ? (lex[tid] - own) : 0;
    float dvn = rsqrtf((float)own + 1.0f);
    if (tid < 256) { lcur[tid] = excl; ldv[tid] = dvn; }
    __syncthreads();
    // pass 2: place src ids into the adj window, wave-parallel
    for (int c = wave; c < nchunks; c += 16) {
        int s0 = offs[(size_t)c * NB1 + b];
        int s1 = offs[(size_t)c * NB1 + b + 1];
        const int* pc = pairs + (size_t)c * CHUNK_P;
        for (int i = s0 + lane; i < s1; i += 64) {
            int pk  = pc[i];
            int pos = atomicAdd(&lcur[pk & 255], 1);
            adj[base + pos] = pk >> BSH;
        }
    }
    int node = node0 + tid;
    if (tid < 256 && node < n) {
        rowinfo[node] = make_int2(base + excl, own);
        dinv[node]    = dvn;
    }
    // ---- tail: hs1[node] *= dinv[node] for this bucket's 256 nodes --------
    for (int u = tid; u < 2048; u += 1024) {
        int nd = node0 + (u >> 3);
        if (nd >= n) break;
        float dv = ldv[u >> 3];
        ushort4* p = (ushort4*)&hs1[((size_t)nd << 6) + (u & 7) * 8];
        ushort4 a = p[0], c = p[1];
        a.x = f2bf(bf2f(a.x) * dv); a.y = f2bf(bf2f(a.y) * dv);
        a.z = f2bf(bf2f(a.z) * dv); a.w = f2bf(bf2f(a.w) * dv);
        c.x = f2bf(bf2f(c.x) * dv); c.y = f2bf(bf2f(c.y) * dv);
        c.z = f2bf(bf2f(c.z) * dv); c.w = f2bf(bf2f(c.w) * dv);
        p[0] = a; p[1] = c;
    }
}

// ---- R4's proven 64-edge gather: named vars u0..u3, 16 rows/wave in flight -
#define GATHER64(PAYLOAD)                                                     \
    for (int base = 0; base < deg; base += 64) {                              \
        int m = deg - base; if (m > 64) m = 64;                               \
        int idx = beg + base + lane;                                          \
        int myoff = adj[idx < AT ? idx : 0] << 6;                             \
        int e = 0;                                                            \
        for (; e + 16 <= m; e += 16) {                                        \
            int o0 = __shfl(myoff, e + grp),     o1 = __shfl(myoff, e + 4 + grp); \
            int o2 = __shfl(myoff, e + 8 + grp), o3 = __shfl(myoff, e + 12 + grp); \
            ushort4 u0 = *(const ushort4*)&PAYLOAD[(size_t)o0 + p4];          \
            ushort4 u1 = *(const ushort4*)&PAYLOAD[(size_t)o1 + p4];          \
            ushort4 u2 = *(const ushort4*)&PAYLOAD[(size_t)o2 + p4];          \
            ushort4 u3 = *(const ushort4*)&PAYLOAD[(size_t)o3 + p4];          \
            acc.x += (bf2f(u0.x) + bf2f(u1.x)) + (bf2f(u2.x) + bf2f(u3.x));   \
            acc.y += (bf2f(u0.y) + bf2f(u1.y)) + (bf2f(u2.y) + bf2f(u3.y));   \
            acc.z += (bf2f(u0.z) + bf2f(u1.z)) + (bf2f(u2.z) + bf2f(u3.z));   \
            acc.w += (bf2f(u0.w) + bf2f(u1.w)) + (bf2f(u2.w) + bf2f(u3.w));   \
        }                                                                     \
        for (; e < m; e += 4) {                                               \
            int sl = e + grp;                                                 \
            int o = __shfl(myoff, sl);                                        \
            if (sl < m) {                                                     \
                ushort4 u = *(const ushort4*)&PAYLOAD[(size_t)o + p4];        \
                acc.x += bf2f(u.x); acc.y += bf2f(u.y);                       \
                acc.z += bf2f(u.z); acc.w += bf2f(u.w);                       \
            }                                                                 \
        }                                                                     \
    }

// ---- layer 1 aggregate fused with TILED layer-2 GEMM -----------------------
// Block = 64 nodes, 512 threads (8 waves x 8 rounds); rowinfo/dinv prefetched
// one round ahead. h1 kept f32 in LDS Htm[m][F1+4]; tiled MM -> hs2.
__global__ __launch_bounds__(512) void k_agg1mm2(
    const int2* __restrict__ rowinfo, const int* __restrict__ adj,
    const unsigned short* __restrict__ hs, const float* __restrict__ dinv,
    const float* __restrict__ b1, const float* __restrict__ W2,
    unsigned short* __restrict__ hs2, int n, int AT) {
    __shared__ float W2s[F1 * FP];       // 16 KB [k][c], cols 41..63 = 0
    __shared__ float Htm[AMT][F1 + 4];   // 17 KB [m][k], pad 4
    int tid  = threadIdx.x;
    int w    = tid >> 6;                 // 8 waves
    int lane = tid & 63;
    int grp  = lane >> 4;
    int p4   = (lane & 15) * 4;
    int n0   = blockIdx.x * AMT;
    // stage W2 (f32); visibility covered by the barrier below
    for (int idx = tid; idx < F1 * FP; idx += 512) {
        int k = idx >> 6, c = idx & 63;
        W2s[idx] = (c < F2) ? W2[k * F2 + c] : 0.f;
    }
    // ---- gather phase: 8 rounds, wave w does node n0 + r*8 + w ------------
    int node = n0 + w;
    int2 ri = make_int2(0, 0);
    float dvn = 0.f;
    if (node < n) { ri = rowinfo[node]; dvn = dinv[node]; }
    for (int r = 0; r < 8; r++) {
        int nl = r * 8 + w;
        // prefetch next round's row metadata (hides one latency hop)
        int node_nx = n0 + (r + 1) * 8 + w;
        int2 ri_nx = make_int2(0, 0);
        float dvn_nx = 0.f;
        if (r < 7 && node_nx < n) { ri_nx = rowinfo[node_nx]; dvn_nx = dinv[node_nx]; }
        float4 acc = {0.f, 0.f, 0.f, 0.f};
        if (node < n) {
            int beg = ri.x, deg = ri.y;
            if (grp == 0) {              // self-loop (pre-scaled)
                ushort4 u = *(const ushort4*)&hs[((size_t)node << 6) + p4];
                acc.x = bf2f(u.x); acc.y = bf2f(u.y);
                acc.z = bf2f(u.z); acc.w = bf2f(u.w);
            }
            GATHER64(hs)
            acc.x += __shfl_xor(acc.x, 16); acc.y += __shfl_xor(acc.y, 16);
            acc.z += __shfl_xor(acc.z, 16); acc.w += __shfl_xor(acc.w, 16);
            acc.x += __shfl_xor(acc.x, 32); acc.y += __shfl_xor(acc.y, 32);
            acc.z += __shfl_xor(acc.z, 32); acc.w += __shfl_xor(acc.w, 32);
        }
        if (grp == 0) {
            float4 v = {0.f, 0.f, 0.f, 0.f};
            if (node < n) {
                float4 bg = *(const float4*)&b1[p4];
                v.x = acc.x * dvn + bg.x; v.x = v.x > 0.f ? v.x : 0.f;
                v.y = acc.y * dvn + bg.y; v.y = v.y > 0.f ? v.y : 0.f;
                v.z = acc.z * dvn + bg.z; v.z = v.z > 0.f ? v.z : 0.f;
                v.w = acc.w * dvn + bg.w; v.w = v.w > 0.f ? v.w : 0.f;
            }
            *(float4*)&Htm[nl][p4] = v;   // contiguous float4/lane: free
        }
        node = node_nx; ri = ri_nx; dvn = dvn_nx;
    }
    __syncthreads();
    // ---- mm2 phase (tiled, 256 threads): thread = rows {ml+16i} x 4 cols --
    if (tid < 256) {
        int ml = tid & 15;
        int c0 = (tid >> 4) * 4;
        float4 r0 = {0.f,0.f,0.f,0.f}, r1 = {0.f,0.f,0.f,0.f};
        float4 r2 = {0.f,0.f,0.f,0.f}, r3 = {0.f,0.f,0.f,0.f};
#pragma unroll
        for (int k = 0; k < F1; k += 4) {
            float4 w0 = *(const float4*)&W2s[(k + 0) * FP + c0];
            float4 w1 = *(const float4*)&W2s[(k + 1) * FP + c0];
            float4 w2 = *(const float4*)&W2s[(k + 2) * FP + c0];
            float4 w3 = *(const float4*)&W2s[(k + 3) * FP + c0];
            float4 a0 = *(const float4*)&Htm[ml     ][k];
            float4 a1 = *(const float4*)&Htm[ml + 16][k];
            float4 a2 = *(const float4*)&Htm[ml + 32][k];
            float4 a3 = *(const float4*)&Htm[ml + 48][k];
#define ACC4(r, a)                                                            \
            r.x += a.x*w0.x + a.y*w1.x + a.z*w2.x + a.w*w3.x;                 \
            r.y += a.x*w0.y + a.y*w1.y + a.z*w2.y + a.w*w3.y;                 \
            r.z += a.x*w0.z + a.y*w1.z + a.z*w2.z + a.w*w3.z;                 \
            r.w += a.x*w0.w + a.y*w1.w + a.z*w2.w + a.w*w3.w;
            ACC4(r0, a0) ACC4(r1, a1) ACC4(r2, a2) ACC4(r3, a3)
#undef ACC4
        }
        float4 rr[4] = {r0, r1, r2, r3};
#pragma unroll
        for (int i = 0; i < 4; i++) {
            int node2 = n0 + ml + 16 * i;
            if (node2 < n) {
                float dv = dinv[node2];
                ushort4 o = { f2bf(rr[i].x * dv), f2bf(rr[i].y * dv),
                              f2bf(rr[i].z * dv), f2bf(rr[i].w * dv) };
                *(ushort4*)&hs2[((size_t)node2 << 6) + c0] = o;
            }
        }
    }
}

// ---- layer 2 aggregate: 32 nodes/block (4 waves x 8 rounds), prefetch -----
__global__ __launch_bounds__(256) void k_agg2(
    const int2* __restrict__ rowinfo, const int* __restrict__ adj,
    const unsigned short* __restrict__ hs2, const float* __restrict__ dinv,
    const float* __restrict__ b2, float* __restrict__ out, int n, int AT) {
    int tid  = threadIdx.x;
    int w    = tid >> 6;                 // 4 waves
    int lane = tid & 63;
    int grp  = lane >> 4;
    int p4   = (lane & 15) * 4;
    int n0   = blockIdx.x * 32;
    int node = n0 + w;
    int2 ri = make_int2(0, 0);
    float dv = 0.f;
    if (node < n) { ri = rowinfo[node]; dv = dinv[node]; }
    for (int r = 0; r < 8; r++) {
        int node_nx = n0 + (r + 1) * 4 + w;
        int2 ri_nx = make_int2(0, 0);
        float dv_nx = 0.f;
        if (r < 7 && node_nx < n) { ri_nx = rowinfo[node_nx]; dv_nx = dinv[node_nx]; }
        float4 acc = {0.f, 0.f, 0.f, 0.f};
        if (node < n) {
            int beg = ri.x, deg = ri.y;
            if (grp == 0) {
                ushort4 u = *(const ushort4*)&hs2[((size_t)node << 6) + p4];
                acc.x = bf2f(u.x); acc.y = bf2f(u.y);
                acc.z = bf2f(u.z); acc.w = bf2f(u.w);
            }
            GATHER64(hs2)
            acc.x += __shfl_xor(acc.x, 16); acc.y += __shfl_xor(acc.y, 16);
            acc.z += __shfl_xor(acc.z, 16); acc.w += __shfl_xor(acc.w, 16);
            acc.x += __shfl_xor(acc.x, 32); acc.y += __shfl_xor(acc.y, 32);
            acc.z += __shfl_xor(acc.z, 32); acc.w += __shfl_xor(acc.w, 32);
            if (grp == 0) {
                float vv[4] = {acc.x, acc.y, acc.z, acc.w};
#pragma unroll
                for (int j = 0; j < 4; j++) {
                    int f = p4 + j;
                    if (f < F2) out[(size_t)node * F2 + f] = vv[j] * dv + b2[f];
                }
            }
        }
        node = node_nx; ri = ri_nx; dv = dv_nx;
    }
}

extern "C" void kernel_launch(void* const* d_in, const int* in_sizes, int n_in,
                              void* d_out, int out_size, void* d_ws, size_t ws_size,
                              hipStream_t stream) {
    const float* x  = (const float*)d_in[0];
    const int*   ei = (const int*)d_in[1];
    const float* W1 = (const float*)d_in[2];
    const float* b1 = (const float*)d_in[3];
    const float* W2 = (const float*)d_in[4];
    const float* b2 = (const float*)d_in[5];
    float* out = (float*)d_out;

    const int n = in_sizes[0] / FIN;   // 100000
    const int E = in_sizes[1] / 2;     // 1600000
    const int* src = ei;
    const int* dst = ei + E;
    const int nbuck   = (n + 255) >> BSH;              // 391
    const int nchunks = (E + CHUNK_P - 1) / CHUNK_P;   // 391
    const int nmm     = (n + MT - 1) / MT;             // 782
    const int nagg1   = (n + AMT - 1) / AMT;           // 1563
    const int nagg2   = (n + 31) / 32;                 // 3125
    const int adjtot  = nbuck * BCAP;

    char* ws = (char*)d_ws;
    size_t off = 0;
    auto alloc = [&](size_t bytes) {
        void* p = ws + off;
        off = (off + bytes + 511) & ~(size_t)511;
        return p;
    };
    unsigned short* offs = (unsigned short*)alloc((size_t)nchunks * (nbuck + 1) * 2);
    int*   pairs   = (int*)alloc((size_t)nchunks * CHUNK_P * 4); // 6.4 MB
    int*   adj     = (int*)alloc((size_t)adjtot * 4 + 256);      // 9.6 MB
    int2*  rowinfo = (int2*)alloc((size_t)n * 8);
    float* dinv    = (float*)alloc((size_t)n * 4);
    unsigned short* hs1 = (unsigned short*)alloc((size_t)n * FP * 2);
    unsigned short* hs2 = (unsigned short*)alloc((size_t)n * FP * 2);

    k_partmm1<<<nchunks + nmm, 256, 0, stream>>>(src, dst, offs, pairs, E, nchunks,
                                                 nbuck, x, W1, hs1, n);
    k_build<<<nbuck, 1024, 0, stream>>>(offs, pairs, nchunks, nbuck, adj, rowinfo,
                                        dinv, hs1, n);
    k_agg1mm2<<<nagg1, 512, 0, stream>>>(rowinfo, adj, hs1, dinv, b1, W2, hs2,
                                         n, adjtot);
    k_agg2<<<nagg2, 256, 0, stream>>>(rowinfo, adj, hs2, dinv, b2, out, n, adjtot);
}

// Round 9
// 281.835 us; speedup vs baseline: 2.5467x; 2.3409x over previous
//
#include <hip/hip_runtime.h>

// GCN 2-layer forward. CSR-gather, bf16 payloads (stride-64, 128 B rows).
// Pipeline (4 dispatches):
//   partmm1 (edge partition + hs1 = bf16(x@W1))
//   build   (1024-thr wave-parallel CSR build + hs1 *= dinv)
//   agg1mm2 (64-node blocks: gather h1 -> f32 LDS, then TILED h1@W2 -> hs2)
//   agg2    (out = dinv*gather + b2)
//
// R9 = verbatim revert to R4 (best measured: 282.8 us). R5-R8 all regressed
// rewriting agg1mm2 (scratch-spill signature: VGPR 128, ~530 MB WRITE); the
// trigger could not be isolated among {Htm float4-store transpose, metadata
// prefetch rotation, gather macro-ization} — R8 disproved the u[16]-array
// theory. Re-anchoring on the proven source; every byte of device code below
// matches R4.

#define FIN 128
#define F1  64
#define F2  41
#define FP  64     // payload row stride (bf16 elems): 128 B, 2 lines, aligned

#define BSH    8                 // bucket = dst >> 8 (256 nodes/bucket)
#define BCAP   6144              // per-bucket adj window (mean 4096, >30 sigma)
#define CHUNK_P 4096             // edges per part block (16/thread)

#define MT 128                   // mm1 GEMM M-tile
#define KC 16                    // mm1 GEMM K-chunk
#define AMT 64                   // agg1mm2 nodes per block

#define SMEM_BYTES 24576         // union: part 19.5 KB / mm1 24.6 KB -> 6 blk/CU

__device__ __forceinline__ unsigned short f2bf(float f) {
    unsigned u = __builtin_bit_cast(unsigned, f);
    u += 0x7FFFu + ((u >> 16) & 1u);           // RNE
    return (unsigned short)(u >> 16);
}
__device__ __forceinline__ float bf2f(unsigned short h) {
    unsigned u = ((unsigned)h) << 16;
    return __builtin_bit_cast(float, u);
}

// ---- fused: blocks [0,nchunks) = edge partition; rest = layer-1 GEMM -------
__global__ __launch_bounds__(256) void k_partmm1(
    const int* __restrict__ src, const int* __restrict__ dst,
    unsigned short* __restrict__ offs, int* __restrict__ pairs,
    int E, int nchunks, int NB,
    const float* __restrict__ x, const float* __restrict__ W1,
    unsigned short* __restrict__ hs, int n) {
    __shared__ alignas(16) char smem[SMEM_BYTES];
    int tid = threadIdx.x;
    if ((int)blockIdx.x < nchunks) {
        // ---------------- PART (19.5 KB): LDS bucket-sort, coalesced out ----
        int* hist = (int*)smem;            // 512 ints (2 KB)
        int* lex  = hist + 512;            // 256 (1 KB)
        int* limg = lex + 256;             // CHUNK_P ints (16 KB)
        int e0  = blockIdx.x * CHUNK_P;
        int ds[CHUNK_P / 256], ss[CHUNK_P / 256];
#pragma unroll
        for (int j = 0; j < CHUNK_P / 256; j++) {
            int e = e0 + j * 256 + tid;
            if (e < E) { ds[j] = dst[e]; ss[j] = src[e]; } else ds[j] = -1;
        }
        hist[tid] = 0; hist[tid + 256] = 0;
        __syncthreads();
#pragma unroll
        for (int j = 0; j < CHUNK_P / 256; j++)
            if (ds[j] >= 0) atomicAdd(&hist[ds[j] >> BSH], 1);
        __syncthreads();
        int b0 = 2 * tid, b1 = 2 * tid + 1;
        int c0 = hist[b0], c1 = hist[b1];
        int s  = c0 + c1;
        lex[tid] = s;
        __syncthreads();
        for (int off = 1; off < 256; off <<= 1) {
            int v = lex[tid];
            int a = (tid >= off) ? lex[tid - off] : 0;
            __syncthreads();
            lex[tid] = v + a;
            __syncthreads();
        }
        int incl = lex[tid];
        int ex0 = incl - s;
        int ex1 = ex0 + c0;
        // per-chunk bucket offset row (u16): starts[b], plus total at [NB]
        unsigned short* orow = offs + (size_t)blockIdx.x * (NB + 1);
        if (b0 < NB) orow[b0] = (unsigned short)ex0;
        if (b1 < NB) orow[b1] = (unsigned short)ex1;
        if (tid == 255) orow[NB] = (unsigned short)incl;
        hist[b0] = ex0; hist[b1] = ex1;
        __syncthreads();
#pragma unroll
        for (int j = 0; j < CHUNK_P / 256; j++) {
            if (ds[j] >= 0) {
                int b = ds[j] >> BSH;
                int p = atomicAdd(&hist[b], 1);
                limg[p] = (ss[j] << BSH) | (ds[j] & 255);
            }
        }
        __syncthreads();
        int tot = lex[255];
        int* pout = pairs + (size_t)blockIdx.x * CHUNK_P;
        for (int k = tid; k < tot; k += 256)   // fully coalesced
            pout[k] = limg[k];
    } else {
        // ---------------- MM1: hs1 = bf16(x @ W1), UNSCALED (24.6 KB) -------
        unsigned short* Ws = (unsigned short*)smem;      // 16 KB, W1 as bf16
        float (*As)[MT] = (float(*)[MT])(smem + FIN * F1 * 2);  // 8 KB
        int n0 = ((int)blockIdx.x - nchunks) * MT;
#pragma unroll
        for (int j = 0; j < 8; j++) {
            int f = j * 256 + tid;                       // float4 index (2048)
            float4 w4 = ((const float4*)W1)[f];
            ushort4 o = { f2bf(w4.x), f2bf(w4.y), f2bf(w4.z), f2bf(w4.w) };
            ((ushort4*)Ws)[f] = o;
        }
        int m0 = (tid & 15) * 8;
        int c0 = (tid >> 4) * 4;
        int m_l = tid & 127;
        int kh  = (tid >> 7) * 8;
        bool mvalid = (n0 + m_l) < n;
        const float* xrow = x + (size_t)(n0 + m_l) * FIN + kh;
        float acc[8][4] = {};
        for (int kc = 0; kc < FIN; kc += KC) {
            __syncthreads();
            float4 v0 = mvalid ? *(const float4*)(xrow + kc)     : float4{0.f,0.f,0.f,0.f};
            float4 v1 = mvalid ? *(const float4*)(xrow + kc + 4) : float4{0.f,0.f,0.f,0.f};
            As[kh + 0][m_l] = v0.x; As[kh + 1][m_l] = v0.y;
            As[kh + 2][m_l] = v0.z; As[kh + 3][m_l] = v0.w;
            As[kh + 4][m_l] = v1.x; As[kh + 5][m_l] = v1.y;
            As[kh + 6][m_l] = v1.z; As[kh + 7][m_l] = v1.w;
            __syncthreads();
#pragma unroll
            for (int k = 0; k < KC; k++) {
                float4 a0 = *(const float4*)&As[k][m0];
                float4 a1 = *(const float4*)&As[k][m0 + 4];
                ushort4 wq = *(const ushort4*)&Ws[(kc + k) * F1 + c0];
                float wx = bf2f(wq.x), wy = bf2f(wq.y);
                float wz = bf2f(wq.z), ww = bf2f(wq.w);
                float a[8] = {a0.x, a0.y, a0.z, a0.w, a1.x, a1.y, a1.z, a1.w};
#pragma unroll
                for (int i = 0; i < 8; i++) {
                    acc[i][0] += a[i] * wx;
                    acc[i][1] += a[i] * wy;
                    acc[i][2] += a[i] * wz;
                    acc[i][3] += a[i] * ww;
                }
            }
        }
#pragma unroll
        for (int i = 0; i < 8; i++) {
            int node = n0 + m0 + i;
            if (node < n) {
                ushort4 o = { f2bf(acc[i][0]), f2bf(acc[i][1]),
                              f2bf(acc[i][2]), f2bf(acc[i][3]) };
                *(ushort4*)&hs[((size_t)node << 6) + c0] = o;
            }
        }
    }
}

// ---- pass 2: wave-parallel per-bucket CSR build + tail-scale hs1 -----------
__global__ __launch_bounds__(1024) void k_build(
    const unsigned short* __restrict__ offs, const int* __restrict__ pairs,
    int nchunks, int NB, int* __restrict__ adj,
    int2* __restrict__ rowinfo, float* __restrict__ dinv,
    unsigned short* __restrict__ hs1, int n) {
    __shared__ int lcnt[256];
    __shared__ int lex[256];
    __shared__ int lcur[256];
    __shared__ float ldv[256];
    int tid  = threadIdx.x;
    int wave = tid >> 6;               // 16 waves
    int lane = tid & 63;
    int b    = blockIdx.x;
    int NB1  = NB + 1;
    int node0 = b << BSH;
    int base  = b * BCAP;              // static adj window

    if (tid < 256) lcnt[tid] = 0;
    __syncthreads();
    // pass 1: per-node histogram; each wave sweeps whole segments
    for (int c = wave; c < nchunks; c += 16) {
        int s0 = offs[(size_t)c * NB1 + b];
        int s1 = offs[(size_t)c * NB1 + b + 1];
        const int* pc = pairs + (size_t)c * CHUNK_P;
        for (int i = s0 + lane; i < s1; i += 64)
            atomicAdd(&lcnt[pc[i] & 255], 1);
    }
    __syncthreads();
    int own = (tid < 256) ? lcnt[tid] : 0;
    if (tid < 256) lex[tid] = own;
    __syncthreads();
    for (int off = 1; off < 256; off <<= 1) {
        int val = 0, add = 0;
        if (tid < 256) {
            val = lex[tid];
            add = (tid >= off) ? lex[tid - off] : 0;
        }
        __syncthreads();
        if (tid < 256) lex[tid] = val + add;
        __syncthreads();
    }
    int excl = (tid < 256) ? (lex[tid] - own) : 0;
    float dvn = rsqrtf((float)own + 1.0f);
    if (tid < 256) { lcur[tid] = excl; ldv[tid] = dvn; }
    __syncthreads();
    // pass 2: place src ids into the adj window, wave-parallel
    for (int c = wave; c < nchunks; c += 16) {
        int s0 = offs[(size_t)c * NB1 + b];
        int s1 = offs[(size_t)c * NB1 + b + 1];
        const int* pc = pairs + (size_t)c * CHUNK_P;
        for (int i = s0 + lane; i < s1; i += 64) {
            int pk  = pc[i];
            int pos = atomicAdd(&lcur[pk & 255], 1);
            adj[base + pos] = pk >> BSH;
        }
    }
    int node = node0 + tid;
    if (tid < 256 && node < n) {
        rowinfo[node] = make_int2(base + excl, own);
        dinv[node]    = dvn;
    }
    // ---- tail: hs1[node] *= dinv[node] for this bucket's 256 nodes --------
    for (int u = tid; u < 2048; u += 1024) {
        int nd = node0 + (u >> 3);
        if (nd >= n) break;
        float dv = ldv[u >> 3];
        ushort4* p = (ushort4*)&hs1[((size_t)nd << 6) + (u & 7) * 8];
        ushort4 a = p[0], c = p[1];
        a.x = f2bf(bf2f(a.x) * dv); a.y = f2bf(bf2f(a.y) * dv);
        a.z = f2bf(bf2f(a.z) * dv); a.w = f2bf(bf2f(a.w) * dv);
        c.x = f2bf(bf2f(c.x) * dv); c.y = f2bf(bf2f(c.y) * dv);
        c.z = f2bf(bf2f(c.z) * dv); c.w = f2bf(bf2f(c.w) * dv);
        p[0] = a; p[1] = c;
    }
}

// ---- layer 1 aggregate fused with TILED layer-2 GEMM -----------------------
// Block = 64 nodes, 512 threads (8 waves x 8 rounds of gathers).
// h1 rows kept f32 in LDS Ht[k][m]; then MT=64 tiled MM -> hs2 (bf16, *dinv).
__global__ __launch_bounds__(512) void k_agg1mm2(
    const int2* __restrict__ rowinfo, const int* __restrict__ adj,
    const unsigned short* __restrict__ hs, const float* __restrict__ dinv,
    const float* __restrict__ b1, const float* __restrict__ W2,
    unsigned short* __restrict__ hs2, int n, int AT) {
    __shared__ float W2s[F1 * FP];       // 16 KB [k][c], cols 41..63 = 0
    __shared__ float Ht[F1][AMT + 4];    // 17 KB [k][m], pad 4 keeps 16B align
    int tid  = threadIdx.x;
    int w    = tid >> 6;                 // 8 waves
    int lane = tid & 63;
    int grp  = lane >> 4;
    int p4   = (lane & 15) * 4;
    int n0   = blockIdx.x * AMT;
    // stage W2 (f32); visibility covered by the barrier below
    for (int idx = tid; idx < F1 * FP; idx += 512) {
        int k = idx >> 6, c = idx & 63;
        W2s[idx] = (c < F2) ? W2[k * F2 + c] : 0.f;
    }
    // ---- gather phase: 8 rounds, wave w does node n0 + r*8 + w ------------
    for (int r = 0; r < 8; r++) {
        int nl   = r * 8 + w;
        int node = n0 + nl;
        float4 acc = {0.f, 0.f, 0.f, 0.f};
        if (node < n) {
            int2 ri = rowinfo[node];
            int beg = ri.x, deg = ri.y;
            if (grp == 0) {              // self-loop (pre-scaled)
                ushort4 u = *(const ushort4*)&hs[((size_t)node << 6) + p4];
                acc.x = bf2f(u.x); acc.y = bf2f(u.y);
                acc.z = bf2f(u.z); acc.w = bf2f(u.w);
            }
            for (int base = 0; base < deg; base += 64) {
                int m = deg - base; if (m > 64) m = 64;
                int idx = beg + base + lane;
                int myoff = adj[idx < AT ? idx : 0] << 6;
                int e = 0;
                for (; e + 16 <= m; e += 16) {
                    int o0 = __shfl(myoff, e + grp),      o1 = __shfl(myoff, e + 4 + grp);
                    int o2 = __shfl(myoff, e + 8 + grp),  o3 = __shfl(myoff, e + 12 + grp);
                    ushort4 u0 = *(const ushort4*)&hs[(size_t)o0 + p4];
                    ushort4 u1 = *(const ushort4*)&hs[(size_t)o1 + p4];
                    ushort4 u2 = *(const ushort4*)&hs[(size_t)o2 + p4];
                    ushort4 u3 = *(const ushort4*)&hs[(size_t)o3 + p4];
                    acc.x += (bf2f(u0.x) + bf2f(u1.x)) + (bf2f(u2.x) + bf2f(u3.x));
                    acc.y += (bf2f(u0.y) + bf2f(u1.y)) + (bf2f(u2.y) + bf2f(u3.y));
                    acc.z += (bf2f(u0.z) + bf2f(u1.z)) + (bf2f(u2.z) + bf2f(u3.z));
                    acc.w += (bf2f(u0.w) + bf2f(u1.w)) + (bf2f(u2.w) + bf2f(u3.w));
                }
                for (; e < m; e += 4) {
                    int sl = e + grp;
                    int o = __shfl(myoff, sl);
                    if (sl < m) {
                        ushort4 u = *(const ushort4*)&hs[(size_t)o + p4];
                        acc.x += bf2f(u.x); acc.y += bf2f(u.y);
                        acc.z += bf2f(u.z); acc.w += bf2f(u.w);
                    }
                }
            }
            acc.x += __shfl_xor(acc.x, 16); acc.y += __shfl_xor(acc.y, 16);
            acc.z += __shfl_xor(acc.z, 16); acc.w += __shfl_xor(acc.w, 16);
            acc.x += __shfl_xor(acc.x, 32); acc.y += __shfl_xor(acc.y, 32);
            acc.z += __shfl_xor(acc.z, 32); acc.w += __shfl_xor(acc.w, 32);
        }
        if (grp == 0) {
            float vx = 0.f, vy = 0.f, vz = 0.f, vw = 0.f;
            if (node < n) {
                float dvn = dinv[node];
                float4 bg = *(const float4*)&b1[p4];
                vx = acc.x * dvn + bg.x; vx = vx > 0.f ? vx : 0.f;
                vy = acc.y * dvn + bg.y; vy = vy > 0.f ? vy : 0.f;
                vz = acc.z * dvn + bg.z; vz = vz > 0.f ? vz : 0.f;
                vw = acc.w * dvn + bg.w; vw = vw > 0.f ? vw : 0.f;
            }
            Ht[p4 + 0][nl] = vx; Ht[p4 + 1][nl] = vy;
            Ht[p4 + 2][nl] = vz; Ht[p4 + 3][nl] = vw;
        }
    }
    __syncthreads();
    // ---- mm2 phase (tiled, 256 threads): thread = 4 rows x 4 cols ---------
    if (tid < 256) {
        int m0 = (tid & 15) * 4;
        int c0 = (tid >> 4) * 4;
        float4 r0 = {0.f,0.f,0.f,0.f}, r1 = {0.f,0.f,0.f,0.f};
        float4 r2 = {0.f,0.f,0.f,0.f}, r3 = {0.f,0.f,0.f,0.f};
#pragma unroll 4
        for (int k = 0; k < F1; k++) {
            float4 av = *(const float4*)&Ht[k][m0];
            float4 wv = *(const float4*)&W2s[(k << 6) + c0];
            r0.x += av.x * wv.x; r0.y += av.x * wv.y; r0.z += av.x * wv.z; r0.w += av.x * wv.w;
            r1.x += av.y * wv.x; r1.y += av.y * wv.y; r1.z += av.y * wv.z; r1.w += av.y * wv.w;
            r2.x += av.z * wv.x; r2.y += av.z * wv.y; r2.z += av.z * wv.z; r2.w += av.z * wv.w;
            r3.x += av.w * wv.x; r3.y += av.w * wv.y; r3.z += av.w * wv.z; r3.w += av.w * wv.w;
        }
        float4 rr[4] = {r0, r1, r2, r3};
#pragma unroll
        for (int i = 0; i < 4; i++) {
            int node = n0 + m0 + i;
            if (node < n) {
                float dv = dinv[node];
                ushort4 o = { f2bf(rr[i].x * dv), f2bf(rr[i].y * dv),
                              f2bf(rr[i].z * dv), f2bf(rr[i].w * dv) };
                *(ushort4*)&hs2[((size_t)node << 6) + c0] = o;
            }
        }
    }
}

// ---- layer 2 aggregate: out = dinv*(gather+self) + b2 ----------------------
__global__ __launch_bounds__(256) void k_agg2(
    const int2* __restrict__ rowinfo, const int* __restrict__ adj,
    const unsigned short* __restrict__ hs2, const float* __restrict__ dinv,
    const float* __restrict__ b2, float* __restrict__ out, int n, int AT) {
    int node = blockIdx.x * 4 + (threadIdx.x >> 6);
    if (node >= n) return;
    int lane = threadIdx.x & 63;
    int grp  = lane >> 4;
    int p4   = (lane & 15) * 4;
    int2 ri = rowinfo[node];
    int beg = ri.x, deg = ri.y;
    float4 acc = {0.f, 0.f, 0.f, 0.f};
    if (grp == 0) {
        ushort4 u = *(const ushort4*)&hs2[((size_t)node << 6) + p4];
        acc.x = bf2f(u.x); acc.y = bf2f(u.y); acc.z = bf2f(u.z); acc.w = bf2f(u.w);
    }
    for (int base = 0; base < deg; base += 64) {
        int m = deg - base; if (m > 64) m = 64;
        int idx = beg + base + lane;
        int myoff = adj[idx < AT ? idx : 0] << 6;
        int e = 0;
        for (; e + 16 <= m; e += 16) {
            int o0 = __shfl(myoff, e + grp),      o1 = __shfl(myoff, e + 4 + grp);
            int o2 = __shfl(myoff, e + 8 + grp),  o3 = __shfl(myoff, e + 12 + grp);
            ushort4 u0 = *(const ushort4*)&hs2[(size_t)o0 + p4];
            ushort4 u1 = *(const ushort4*)&hs2[(size_t)o1 + p4];
            ushort4 u2 = *(const ushort4*)&hs2[(size_t)o2 + p4];
            ushort4 u3 = *(const ushort4*)&hs2[(size_t)o3 + p4];
            acc.x += (bf2f(u0.x) + bf2f(u1.x)) + (bf2f(u2.x) + bf2f(u3.x));
            acc.y += (bf2f(u0.y) + bf2f(u1.y)) + (bf2f(u2.y) + bf2f(u3.y));
            acc.z += (bf2f(u0.z) + bf2f(u1.z)) + (bf2f(u2.z) + bf2f(u3.z));
            acc.w += (bf2f(u0.w) + bf2f(u1.w)) + (bf2f(u2.w) + bf2f(u3.w));
        }
        for (; e < m; e += 4) {
            int sl = e + grp;
            int o = __shfl(myoff, sl);
            if (sl < m) {
                ushort4 u = *(const ushort4*)&hs2[(size_t)o + p4];
                acc.x += bf2f(u.x); acc.y += bf2f(u.y);
                acc.z += bf2f(u.z); acc.w += bf2f(u.w);
            }
        }
    }
    acc.x += __shfl_xor(acc.x, 16); acc.y += __shfl_xor(acc.y, 16);
    acc.z += __shfl_xor(acc.z, 16); acc.w += __shfl_xor(acc.w, 16);
    acc.x += __shfl_xor(acc.x, 32); acc.y += __shfl_xor(acc.y, 32);
    acc.z += __shfl_xor(acc.z, 32); acc.w += __shfl_xor(acc.w, 32);
    if (grp == 0) {
        float dv = dinv[node];
        float vv[4] = {acc.x, acc.y, acc.z, acc.w};
#pragma unroll
        for (int j = 0; j < 4; j++) {
            int f = p4 + j;
            if (f < F2) out[(size_t)node * F2 + f] = vv[j] * dv + b2[f];
        }
    }
}

extern "C" void kernel_launch(void* const* d_in, const int* in_sizes, int n_in,
                              void* d_out, int out_size, void* d_ws, size_t ws_size,
                              hipStream_t stream) {
    const float* x  = (const float*)d_in[0];
    const int*   ei = (const int*)d_in[1];
    const float* W1 = (const float*)d_in[2];
    const float* b1 = (const float*)d_in[3];
    const float* W2 = (const float*)d_in[4];
    const float* b2 = (const float*)d_in[5];
    float* out = (float*)d_out;

    const int n = in_sizes[0] / FIN;   // 100000
    const int E = in_sizes[1] / 2;     // 1600000
    const int* src = ei;
    const int* dst = ei + E;
    const int nbuck   = (n + 255) >> BSH;              // 391
    const int nchunks = (E + CHUNK_P - 1) / CHUNK_P;   // 391
    const int nmm     = (n + MT - 1) / MT;             // 782
    const int nagg1   = (n + AMT - 1) / AMT;           // 1563
    const int nagg    = (n + 3) / 4;                   // 25000
    const int adjtot  = nbuck * BCAP;

    char* ws = (char*)d_ws;
    size_t off = 0;
    auto alloc = [&](size_t bytes) {
        void* p = ws + off;
        off = (off + bytes + 511) & ~(size_t)511;
        return p;
    };
    unsigned short* offs = (unsigned short*)alloc((size_t)nchunks * (nbuck + 1) * 2);
    int*   pairs   = (int*)alloc((size_t)nchunks * CHUNK_P * 4); // 6.4 MB
    int*   adj     = (int*)alloc((size_t)adjtot * 4 + 256);      // 9.6 MB
    int2*  rowinfo = (int2*)alloc((size_t)n * 8);
    float* dinv    = (float*)alloc((size_t)n * 4);
    unsigned short* hs1 = (unsigned short*)alloc((size_t)n * FP * 2);
    unsigned short* hs2 = (unsigned short*)alloc((size_t)n * FP * 2);

    k_partmm1<<<nchunks + nmm, 256, 0, stream>>>(src, dst, offs, pairs, E, nchunks,
                                                 nbuck, x, W1, hs1, n);
    k_build<<<nbuck, 1024, 0, stream>>>(offs, pairs, nchunks, nbuck, adj, rowinfo,
                                        dinv, hs1, n);
    k_agg1mm2<<<nagg1, 512, 0, stream>>>(rowinfo, adj, hs1, dinv, b1, W2, hs2,
                                         n, adjtot);
    k_agg2<<<nagg, 256, 0, stream>>>(rowinfo, adj, hs2, dinv, b2, out, n, adjtot);
}